// Round 1
// baseline (226.801 us; speedup 1.0000x reference)
//
#include <hip/hip_runtime.h>
#include <hip/hip_bf16.h>
#include <stdint.h>

typedef __bf16 bf16;
typedef __bf16 bf16x8 __attribute__((ext_vector_type(8)));
typedef float f32x4 __attribute__((ext_vector_type(4)));

#define TAU (1.0f/30.0f)

#define NB 32
#define CI 256
#define CO 256
#define HH 64
#define WW 64
#define HID 64

// wn fragment-linear layout: [n][c(8 ci-chunks)][kk(9)][cbg(16)][lane(64)][j(8)]
//   element(n,c,kk,cbg,lane,j) = sum_m pi[n][m]*Wbank[co=cbg*16+(lane&15)][m][ci=c*32+(lane>>4)*8+j][kk]
#define WN_ELEMS ((size_t)NB*8*9*16*512)
#define WN_BYTES (WN_ELEMS*2)

__global__ void pool_kernel(const float* __restrict__ x, float* __restrict__ pooled) {
  int wv = threadIdx.x >> 6, lane = threadIdx.x & 63;
  int idx = blockIdx.x * 4 + wv;              // n*256+ci
  const float4* p = (const float4*)(x + (size_t)idx * 4096);
  float s = 0.f;
#pragma unroll
  for (int i = 0; i < 16; ++i) {
    float4 v = p[lane + 64*i];
    s += v.x + v.y + v.z + v.w;
  }
#pragma unroll
  for (int off = 32; off; off >>= 1) s += __shfl_xor(s, off);
  if (lane == 0) pooled[idx] = s * (1.0f/4096.0f);
}

__global__ void attn_kernel(const float* __restrict__ pooled,
                            const float* __restrict__ w1, const float* __restrict__ b1,
                            const float* __restrict__ w2, const float* __restrict__ b2,
                            float* __restrict__ pi) {
  int n = blockIdx.x, h = threadIdx.x;        // 64 threads
  __shared__ float hm[HID];
  __shared__ float lgs[4];
  const float* pr = pooled + n*CI;
  float s = b1[h];
  for (int c = 0; c < CI; ++c) s += pr[c] * w1[h*CI + c];
  hm[h] = s > 0.f ? s : 0.f;
  __syncthreads();
  if (h < 4) {
    float lg = b2[h];
    for (int k = 0; k < HID; ++k) lg += hm[k] * w2[h*HID + k];
    lgs[h] = lg * TAU;
  }
  __syncthreads();
  if (h == 0) {
    float mx = fmaxf(fmaxf(lgs[0], lgs[1]), fmaxf(lgs[2], lgs[3]));
    float e0 = expf(lgs[0]-mx), e1 = expf(lgs[1]-mx), e2 = expf(lgs[2]-mx), e3 = expf(lgs[3]-mx);
    float inv = 1.f / (e0+e1+e2+e3);
    pi[n*4+0] = e0*inv; pi[n*4+1] = e1*inv; pi[n*4+2] = e2*inv; pi[n*4+3] = e3*inv;
  }
}

// One wave per (c,kk,cbg): loads Wbank fragment once (32 floats/lane), loops n=0..31,
// writes 1KB coalesced per n.
__global__ void agg_kernel(const float* __restrict__ Wbank, const float* __restrict__ pi,
                           bf16* __restrict__ wn) {
  int wid = blockIdx.x * 4 + (threadIdx.x >> 6);   // 0..1151
  int lane = threadIdx.x & 63;
  int c = wid / 144;
  int rem = wid - c*144;
  int kk = rem >> 4;
  int cbg = rem & 15;
  int co  = cbg*16 + (lane & 15);
  int ci0 = c*32 + (lane >> 4)*8;
  float w[4][8];
#pragma unroll
  for (int m = 0; m < 4; ++m)
#pragma unroll
    for (int j = 0; j < 8; ++j)
      w[m][j] = Wbank[(size_t)((co*4 + m)*256 + ci0 + j)*9 + kk];
  for (int n = 0; n < NB; ++n) {
    float p0 = pi[n*4+0], p1 = pi[n*4+1], p2 = pi[n*4+2], p3 = pi[n*4+3];
    bf16x8 o;
#pragma unroll
    for (int j = 0; j < 8; ++j)
      o[j] = (bf16)(p0*w[0][j] + p1*w[1][j] + p2*w[2][j] + p3*w[3][j]);
    *(bf16x8*)(wn + ((size_t)n*1152 + c*144 + kk*16 + cbg)*512 + lane*8) = o;
  }
}

// Conv: block = (hwb: 4 image rows, cot: 64 co, n). 4 waves; wave wv owns image row h0+wv,
// wave tile 64co x 64hw = 4x4 fragments of mfma_f32_16x16x32_bf16.
// xs layout: [g(4 ci-groups)][r(6 rows: h0-1..h0+4)][wl(66: w+1, halo at 0/65)][j(8 ci)] bf16
// wa layout: [kk(9)][cb(4)][lane(64)][j(8)] bf16 (fragment-linear, matches wn)
#define XSLOTS (4*6*66)

__global__ __launch_bounds__(256, 2)
void conv_kernel(const float* __restrict__ x, const bf16* __restrict__ wn,
                 const float* __restrict__ pi, const float* __restrict__ Bbank,
                 float* __restrict__ y) {
  __shared__ __align__(16) bf16 xs[XSLOTS*8];     // 25344 B
  __shared__ __align__(16) bf16 wa[9*4*512];      // 36864 B
  __shared__ float bns[64];
  const int tid = threadIdx.x;
  const int wv = tid >> 6, lane = tid & 63;
  const int hwb = blockIdx.x;   // 0..15
  const int cot = blockIdx.y;   // 0..3
  const int n   = blockIdx.z;   // 0..31
  const int h0 = hwb * 4;

  // one-time zero: halo columns (wl=0,65) and out-of-range rows stay zero forever
  for (int i = tid; i < XSLOTS*8; i += 256) xs[i] = (bf16)0.f;
  if (tid < 64) {
    int co = cot*64 + tid;
    bns[tid] = pi[n*4+0]*Bbank[co*4+0] + pi[n*4+1]*Bbank[co*4+1]
             + pi[n*4+2]*Bbank[co*4+2] + pi[n*4+3]*Bbank[co*4+3];
  }

  f32x4 acc[4][4];
#pragma unroll
  for (int a = 0; a < 4; ++a)
#pragma unroll
    for (int b = 0; b < 4; ++b)
#pragma unroll
      for (int k = 0; k < 4; ++k) acc[a][b][k] = 0.f;

  const float* xn = x + (size_t)n * CI * HH * WW;
  const bf16* wnb = wn + (size_t)n * 1152 * 512;
  const int w_ = tid & 63;       // staging: lane = w column (coalesced loads, conflict-free b128 LDS writes)
  const int sg = tid >> 6;       // staging: ci-group

  for (int c = 0; c < 8; ++c) {
    __syncthreads();             // previous chunk's compute done before overwrite
    // stage weights: fragment-linear, contiguous 16B/lane
    {
      const bf16* seg = wnb + (size_t)c * 144 * 512;
#pragma unroll
      for (int kk = 0; kk < 9; ++kk) {
        int4 v = *(const int4*)(seg + (kk*16 + cot*4 + wv)*512 + lane*8);
        *(int4*)(&wa[kk*2048 + wv*512 + lane*8]) = v;
      }
    }
    // stage x slab: per wave its ci-group, 6 rows, 64 w; pack 8 ci -> one ds_write_b128
    {
#pragma unroll
      for (int r = 0; r < 6; ++r) {
        int hp = h0 - 1 + r;
        if (hp >= 0 && hp < HH) {
          bf16x8 o;
#pragma unroll
          for (int j = 0; j < 8; ++j) {
            int ci = c*32 + sg*8 + j;
            o[j] = (bf16)xn[((size_t)ci*HH + hp)*WW + w_];
          }
          *(bf16x8*)(&xs[(((sg*6 + r)*66) + (w_ + 1)) * 8]) = o;
        }
      }
    }
    __syncthreads();
    // compute: 9 taps x (4 B-frags + 4 A-frags) -> 16 MFMA per tap
#pragma unroll
    for (int ky = 0; ky < 3; ++ky) {
#pragma unroll
      for (int kx = 0; kx < 3; ++kx) {
        const int kk = ky*3 + kx;
        const int r = wv + ky;
        bf16x8 bfr[4];
#pragma unroll
        for (int f = 0; f < 4; ++f) {
          int wl = f*16 + (lane & 15) + kx;
          bfr[f] = *(const bf16x8*)(&xs[(((lane >> 4)*6 + r)*66 + wl) * 8]);
        }
#pragma unroll
        for (int cb = 0; cb < 4; ++cb) {
          bf16x8 afr = *(const bf16x8*)(&wa[kk*2048 + cb*512 + lane*8]);
#pragma unroll
          for (int f = 0; f < 4; ++f)
            acc[cb][f] = __builtin_amdgcn_mfma_f32_16x16x32_bf16(afr, bfr[f], acc[cb][f], 0, 0, 0);
        }
      }
    }
  }
  // epilogue: D row=(lane>>4)*4+reg -> co, col=lane&15 -> w
  const int h = h0 + wv;
#pragma unroll
  for (int cb = 0; cb < 4; ++cb) {
#pragma unroll
    for (int f = 0; f < 4; ++f) {
      const int wcol = f*16 + (lane & 15);
#pragma unroll
      for (int r4 = 0; r4 < 4; ++r4) {
        const int col = cb*16 + (lane >> 4)*4 + r4;
        y[(((size_t)n*CO + cot*64 + col)*HH + h)*WW + wcol] = acc[cb][f][r4] + bns[col];
      }
    }
  }
}

extern "C" void kernel_launch(void* const* d_in, const int* in_sizes, int n_in,
                              void* d_out, int out_size, void* d_ws, size_t ws_size,
                              hipStream_t stream) {
  const float* x     = (const float*)d_in[0];
  const float* Wbank = (const float*)d_in[1];
  const float* Bbank = (const float*)d_in[2];
  const float* w1    = (const float*)d_in[3];
  const float* b1    = (const float*)d_in[4];
  const float* w2    = (const float*)d_in[5];
  const float* b2    = (const float*)d_in[6];
  float* y = (float*)d_out;

  bf16*  wn     = (bf16*)d_ws;                       // 37,748,736 B
  float* pooled = (float*)((char*)d_ws + WN_BYTES);  // 32 KB
  float* pi     = pooled + NB*CI;                    // 512 B

  pool_kernel<<<2048, 256, 0, stream>>>(x, pooled);
  attn_kernel<<<NB, HID, 0, stream>>>(pooled, w1, b1, w2, b2, pi);
  agg_kernel<<<288, 256, 0, stream>>>(Wbank, pi, wn);
  dim3 grid(16, 4, NB);
  conv_kernel<<<grid, 256, 0, stream>>>(x, wn, pi, Bbank, y);
}

// Round 2
// 199.519 us; speedup vs baseline: 1.1367x; 1.1367x over previous
//
#include <hip/hip_runtime.h>
#include <hip/hip_bf16.h>
#include <stdint.h>

typedef __bf16 bf16;
typedef __bf16 bf16x8 __attribute__((ext_vector_type(8)));
typedef float f32x4 __attribute__((ext_vector_type(4)));

#define TAU (1.0f/30.0f)

#define NB 32
#define CI 256
#define CO 256
#define HH 64
#define WW 64
#define HID 64

// wn fragment-linear layout: [n][c(8 ci-chunks)][kk(9)][cbg(16)][lane(64)][j(8)]
#define WN_ELEMS ((size_t)NB*8*9*16*512)
#define WN_BYTES (WN_ELEMS*2)
// xb packed layout: [n][cg(32 ci-groups of 8)][h(64)][w(64)][j(8)] bf16
#define XB_ELEMS ((size_t)NB*32*64*64*8)
#define XB_BYTES (XB_ELEMS*2)

__device__ __forceinline__ void async16(void* lds_uniform_base, const void* g_perlane) {
  __builtin_amdgcn_global_load_lds(
      (const __attribute__((address_space(1))) uint32_t*)g_perlane,
      (__attribute__((address_space(3))) uint32_t*)lds_uniform_base, 16, 0, 0);
}

// Fused fp32->bf16 repack + global average pool.
// block = (cg, n); reads 8 ci planes, writes packed bf16, reduces 8 sums.
__global__ void cvt_pool_kernel(const float* __restrict__ x, bf16* __restrict__ xb,
                                float* __restrict__ pooled) {
  const int cg = blockIdx.x, n = blockIdx.y, tid = threadIdx.x;
  const float* base = x + ((size_t)n*CI + cg*8)*4096;
  bf16* ob = xb + ((size_t)n*32 + cg)*4096*8;
  float s[8];
#pragma unroll
  for (int j = 0; j < 8; ++j) s[j] = 0.f;
  for (int it = 0; it < 16; ++it) {
    int pos = it*256 + tid;
    bf16x8 o;
#pragma unroll
    for (int j = 0; j < 8; ++j) {
      float v = base[(size_t)j*4096 + pos];
      s[j] += v;
      o[j] = (bf16)v;
    }
    *(bf16x8*)(ob + (size_t)pos*8) = o;
  }
  __shared__ float red[4][8];
#pragma unroll
  for (int j = 0; j < 8; ++j)
#pragma unroll
    for (int off = 32; off; off >>= 1) s[j] += __shfl_xor(s[j], off);
  int wv = tid >> 6, lane = tid & 63;
  if (lane == 0)
#pragma unroll
    for (int j = 0; j < 8; ++j) red[wv][j] = s[j];
  __syncthreads();
  if (tid < 8) {
    float t = red[0][tid] + red[1][tid] + red[2][tid] + red[3][tid];
    pooled[n*CI + cg*8 + tid] = t * (1.0f/4096.0f);
  }
}

__global__ void attn_kernel(const float* __restrict__ pooled,
                            const float* __restrict__ w1, const float* __restrict__ b1,
                            const float* __restrict__ w2, const float* __restrict__ b2,
                            float* __restrict__ pi) {
  int n = blockIdx.x, h = threadIdx.x;        // 64 threads
  __shared__ float hm[HID];
  __shared__ float lgs[4];
  const float* pr = pooled + n*CI;
  float s = b1[h];
  for (int c = 0; c < CI; ++c) s += pr[c] * w1[h*CI + c];
  hm[h] = s > 0.f ? s : 0.f;
  __syncthreads();
  if (h < 4) {
    float lg = b2[h];
    for (int k = 0; k < HID; ++k) lg += hm[k] * w2[h*HID + k];
    lgs[h] = lg * TAU;
  }
  __syncthreads();
  if (h == 0) {
    float mx = fmaxf(fmaxf(lgs[0], lgs[1]), fmaxf(lgs[2], lgs[3]));
    float e0 = expf(lgs[0]-mx), e1 = expf(lgs[1]-mx), e2 = expf(lgs[2]-mx), e3 = expf(lgs[3]-mx);
    float inv = 1.f / (e0+e1+e2+e3);
    pi[n*4+0] = e0*inv; pi[n*4+1] = e1*inv; pi[n*4+2] = e2*inv; pi[n*4+3] = e3*inv;
  }
}

__global__ void agg_kernel(const float* __restrict__ Wbank, const float* __restrict__ pi,
                           bf16* __restrict__ wn) {
  int wid = blockIdx.x * 4 + (threadIdx.x >> 6);   // 0..1151
  int lane = threadIdx.x & 63;
  int c = wid / 144;
  int rem = wid - c*144;
  int kk = rem >> 4;
  int cbg = rem & 15;
  int co  = cbg*16 + (lane & 15);
  int ci0 = c*32 + (lane >> 4)*8;
  float w[4][8];
#pragma unroll
  for (int m = 0; m < 4; ++m)
#pragma unroll
    for (int j = 0; j < 8; ++j)
      w[m][j] = Wbank[(size_t)((co*4 + m)*256 + ci0 + j)*9 + kk];
  for (int n = 0; n < NB; ++n) {
    float p0 = pi[n*4+0], p1 = pi[n*4+1], p2 = pi[n*4+2], p3 = pi[n*4+3];
    bf16x8 o;
#pragma unroll
    for (int j = 0; j < 8; ++j)
      o[j] = (bf16)(p0*w[0][j] + p1*w[1][j] + p2*w[2][j] + p3*w[3][j]);
    *(bf16x8*)(wn + ((size_t)n*1152 + c*144 + kk*16 + cbg)*512 + lane*8) = o;
  }
}

// Conv: block = (hwb: 4 image rows, cot: 64 co, n). 4 waves; wave wv owns image row h0+wv.
// xs layout: [g(4 ci-groups)][r(6 rows)][wl(66: w+1, halo 0/65)][j(8 ci)] bf16
// wa layout: [kk(9)][cb(4)][lane(64)][j(8)] bf16
#define XSLOTS (4*6*66)

__global__ __launch_bounds__(256, 2)
void conv_kernel(const bf16* __restrict__ xb, const bf16* __restrict__ wn,
                 const float* __restrict__ pi, const float* __restrict__ Bbank,
                 float* __restrict__ y) {
  __shared__ __align__(16) bf16 xs[XSLOTS*8];     // 25344 B
  __shared__ __align__(16) bf16 wa[9*4*512];      // 36864 B
  __shared__ float bns[64];
  const int tid = threadIdx.x;
  const int wv = tid >> 6, lane = tid & 63;
  const int hwb = blockIdx.x;   // 0..15
  const int cot = blockIdx.y;   // 0..3
  const int n   = blockIdx.z;   // 0..31
  const int h0 = hwb * 4;

  // one-time zero: halo columns (wl=0,65) and out-of-range rows stay zero forever
  for (int i = tid; i < XSLOTS*8; i += 256) xs[i] = (bf16)0.f;
  if (tid < 64) {
    int co = cot*64 + tid;
    bns[tid] = pi[n*4+0]*Bbank[co*4+0] + pi[n*4+1]*Bbank[co*4+1]
             + pi[n*4+2]*Bbank[co*4+2] + pi[n*4+3]*Bbank[co*4+3];
  }

  f32x4 acc[4][4];
#pragma unroll
  for (int a = 0; a < 4; ++a)
#pragma unroll
    for (int b = 0; b < 4; ++b)
#pragma unroll
      for (int k = 0; k < 4; ++k) acc[a][b][k] = 0.f;

  const bf16* wnb = wn + (size_t)n * 1152 * 512;
  const int sg = wv;             // staging: each wave stages its ci-group

  for (int c = 0; c < 8; ++c) {
    __syncthreads();             // previous chunk's compute done before overwrite
    // stage weights: 9x global_load_lds width=16, LDS dest wave-uniform
    {
      const bf16* seg = wnb + (size_t)c*144*512 + (size_t)(cot*4 + wv)*512 + lane*8;
#pragma unroll
      for (int kk = 0; kk < 9; ++kk)
        async16(&wa[kk*2048 + wv*512], seg + (size_t)kk*16*512);
    }
    // stage x rows: per wave its ci-group, up to 6 rows, 1KB each
    {
      const bf16* xg = xb + ((size_t)(n*32 + c*4 + sg))*4096*8 + lane*8;
#pragma unroll
      for (int r = 0; r < 6; ++r) {
        int hp = h0 - 1 + r;
        if (hp >= 0 && hp < HH)
          async16(&xs[(((sg*6 + r)*66) + 1)*8], xg + (size_t)hp*64*8);
      }
    }
    __syncthreads();             // waits vmcnt(0) before barrier
    // compute: 9 taps x (4 B-frags + 4 A-frags) -> 16 MFMA per tap
#pragma unroll
    for (int ky = 0; ky < 3; ++ky) {
#pragma unroll
      for (int kx = 0; kx < 3; ++kx) {
        const int kk = ky*3 + kx;
        const int r = wv + ky;
        bf16x8 bfr[4];
#pragma unroll
        for (int f = 0; f < 4; ++f) {
          int wl = f*16 + (lane & 15) + kx;
          bfr[f] = *(const bf16x8*)(&xs[(((lane >> 4)*6 + r)*66 + wl) * 8]);
        }
#pragma unroll
        for (int cb = 0; cb < 4; ++cb) {
          bf16x8 afr = *(const bf16x8*)(&wa[kk*2048 + cb*512 + lane*8]);
#pragma unroll
          for (int f = 0; f < 4; ++f)
            acc[cb][f] = __builtin_amdgcn_mfma_f32_16x16x32_bf16(afr, bfr[f], acc[cb][f], 0, 0, 0);
        }
      }
    }
  }
  // epilogue: D row=(lane>>4)*4+reg -> co, col=lane&15 -> w
  const int h = h0 + wv;
#pragma unroll
  for (int cb = 0; cb < 4; ++cb) {
#pragma unroll
    for (int f = 0; f < 4; ++f) {
      const int wcol = f*16 + (lane & 15);
#pragma unroll
      for (int r4 = 0; r4 < 4; ++r4) {
        const int col = cb*16 + (lane >> 4)*4 + r4;
        y[(((size_t)n*CO + cot*64 + col)*HH + h)*WW + wcol] = acc[cb][f][r4] + bns[col];
      }
    }
  }
}

extern "C" void kernel_launch(void* const* d_in, const int* in_sizes, int n_in,
                              void* d_out, int out_size, void* d_ws, size_t ws_size,
                              hipStream_t stream) {
  const float* x     = (const float*)d_in[0];
  const float* Wbank = (const float*)d_in[1];
  const float* Bbank = (const float*)d_in[2];
  const float* w1    = (const float*)d_in[3];
  const float* b1    = (const float*)d_in[4];
  const float* w2    = (const float*)d_in[5];
  const float* b2    = (const float*)d_in[6];
  float* y = (float*)d_out;

  bf16*  wn     = (bf16*)d_ws;                                  // 37.75 MB
  bf16*  xb     = (bf16*)((char*)d_ws + WN_BYTES);              // 64 MB
  float* pooled = (float*)((char*)d_ws + WN_BYTES + XB_BYTES);  // 32 KB
  float* pi     = pooled + NB*CI;                               // 512 B

  dim3 cg(32, NB);
  cvt_pool_kernel<<<cg, 256, 0, stream>>>(x, xb, pooled);
  attn_kernel<<<NB, HID, 0, stream>>>(pooled, w1, b1, w2, b2, pi);
  agg_kernel<<<288, 256, 0, stream>>>(Wbank, pi, wn);
  dim3 grid(16, 4, NB);
  conv_kernel<<<grid, 256, 0, stream>>>(xb, wn, pi, Bbank, y);
}

// Round 3
// 190.363 us; speedup vs baseline: 1.1914x; 1.0481x over previous
//
#include <hip/hip_runtime.h>
#include <hip/hip_bf16.h>
#include <stdint.h>

typedef __bf16 bf16;
typedef __bf16 bf16x8 __attribute__((ext_vector_type(8)));
typedef float f32x4 __attribute__((ext_vector_type(4)));

#define TAU (1.0f/30.0f)

#define NB 32
#define CI 256
#define CO 256
#define HH 64
#define WW 64
#define HID 64

// wn fragment-linear layout: [n][c(8 ci-chunks)][kk(9)][cbg(16)][lane(64)][j(8)]
#define WN_ELEMS ((size_t)NB*8*9*16*512)
#define WN_BYTES (WN_ELEMS*2)
// xb packed layout: [n][cg(32 ci-groups of 8)][h(64)][w(64)][j(8)] bf16
#define XB_ELEMS ((size_t)NB*32*64*64*8)
#define XB_BYTES (XB_ELEMS*2)

__device__ __forceinline__ void async16(void* lds_uniform_base, const void* g_perlane) {
  __builtin_amdgcn_global_load_lds(
      (const __attribute__((address_space(1))) uint32_t*)g_perlane,
      (__attribute__((address_space(3))) uint32_t*)lds_uniform_base, 16, 0, 0);
}

// Fused fp32->bf16 repack + global average pool.
__global__ void cvt_pool_kernel(const float* __restrict__ x, bf16* __restrict__ xb,
                                float* __restrict__ pooled) {
  const int cg = blockIdx.x, n = blockIdx.y, tid = threadIdx.x;
  const float* base = x + ((size_t)n*CI + cg*8)*4096;
  bf16* ob = xb + ((size_t)n*32 + cg)*4096*8;
  float s[8];
#pragma unroll
  for (int j = 0; j < 8; ++j) s[j] = 0.f;
  for (int it = 0; it < 16; ++it) {
    int pos = it*256 + tid;
    bf16x8 o;
#pragma unroll
    for (int j = 0; j < 8; ++j) {
      float v = base[(size_t)j*4096 + pos];
      s[j] += v;
      o[j] = (bf16)v;
    }
    *(bf16x8*)(ob + (size_t)pos*8) = o;
  }
  __shared__ float red[4][8];
#pragma unroll
  for (int j = 0; j < 8; ++j)
#pragma unroll
    for (int off = 32; off; off >>= 1) s[j] += __shfl_xor(s[j], off);
  int wv = tid >> 6, lane = tid & 63;
  if (lane == 0)
#pragma unroll
    for (int j = 0; j < 8; ++j) red[wv][j] = s[j];
  __syncthreads();
  if (tid < 8) {
    float t = red[0][tid] + red[1][tid] + red[2][tid] + red[3][tid];
    pooled[n*CI + cg*8 + tid] = t * (1.0f/4096.0f);
  }
}

__global__ void attn_kernel(const float* __restrict__ pooled,
                            const float* __restrict__ w1, const float* __restrict__ b1,
                            const float* __restrict__ w2, const float* __restrict__ b2,
                            float* __restrict__ pi) {
  int n = blockIdx.x, h = threadIdx.x;        // 64 threads
  __shared__ float hm[HID];
  __shared__ float lgs[4];
  const float* pr = pooled + n*CI;
  float s = b1[h];
  for (int c = 0; c < CI; ++c) s += pr[c] * w1[h*CI + c];
  hm[h] = s > 0.f ? s : 0.f;
  __syncthreads();
  if (h < 4) {
    float lg = b2[h];
    for (int k = 0; k < HID; ++k) lg += hm[k] * w2[h*HID + k];
    lgs[h] = lg * TAU;
  }
  __syncthreads();
  if (h == 0) {
    float mx = fmaxf(fmaxf(lgs[0], lgs[1]), fmaxf(lgs[2], lgs[3]));
    float e0 = expf(lgs[0]-mx), e1 = expf(lgs[1]-mx), e2 = expf(lgs[2]-mx), e3 = expf(lgs[3]-mx);
    float inv = 1.f / (e0+e1+e2+e3);
    pi[n*4+0] = e0*inv; pi[n*4+1] = e1*inv; pi[n*4+2] = e2*inv; pi[n*4+3] = e3*inv;
  }
}

__global__ void agg_kernel(const float* __restrict__ Wbank, const float* __restrict__ pi,
                           bf16* __restrict__ wn) {
  int wid = blockIdx.x * 4 + (threadIdx.x >> 6);   // 0..1151
  int lane = threadIdx.x & 63;
  int c = wid / 144;
  int rem = wid - c*144;
  int kk = rem >> 4;
  int cbg = rem & 15;
  int co  = cbg*16 + (lane & 15);
  int ci0 = c*32 + (lane >> 4)*8;
  float w[4][8];
#pragma unroll
  for (int m = 0; m < 4; ++m)
#pragma unroll
    for (int j = 0; j < 8; ++j)
      w[m][j] = Wbank[(size_t)((co*4 + m)*256 + ci0 + j)*9 + kk];
  for (int n = 0; n < NB; ++n) {
    float p0 = pi[n*4+0], p1 = pi[n*4+1], p2 = pi[n*4+2], p3 = pi[n*4+3];
    bf16x8 o;
#pragma unroll
    for (int j = 0; j < 8; ++j)
      o[j] = (bf16)(p0*w[0][j] + p1*w[1][j] + p2*w[2][j] + p3*w[3][j]);
    *(bf16x8*)(wn + ((size_t)n*1152 + c*144 + kk*16 + cbg)*512 + lane*8) = o;
  }
}

// Conv: block = 8 image rows x 64 co; 4 waves, wave wv owns rows h0+wv*2, h0+wv*2+1.
// xs layout: [g(4 ci-groups)][r(10 rows: h0-1..h0+8)][wl(66)][j(8 ci)] bf16
// wa layout: [kk(9)][cb(4)][lane(64)][j(8)] bf16
#define XROWS 10
#define XW 66

__global__ __launch_bounds__(256, 2)
void conv_kernel(const bf16* __restrict__ xb, const bf16* __restrict__ wn,
                 const float* __restrict__ pi, const float* __restrict__ Bbank,
                 float* __restrict__ y) {
  __shared__ __align__(16) bf16 xs[4*XROWS*XW*8];   // 42240 B
  __shared__ __align__(16) bf16 wa[9*4*512];        // 36864 B
  __shared__ float bns[64];
  const int tid = threadIdx.x;
  const int wv = tid >> 6, lane = tid & 63;
  const int l = lane & 15, u = lane >> 4;
  const int hwb = blockIdx.x;   // 0..7
  const int cot = blockIdx.y;   // 0..3
  const int n   = blockIdx.z;   // 0..31
  const int h0 = hwb * 8;

  // one-time zero: halo columns (wl=0,65) and out-of-range rows stay zero forever
  for (int i = tid; i < 4*XROWS*XW*8/8; i += 256) ((int4*)xs)[i] = int4{0,0,0,0};
  if (tid < 64) {
    int co = cot*64 + tid;
    bns[tid] = pi[n*4+0]*Bbank[co*4+0] + pi[n*4+1]*Bbank[co*4+1]
             + pi[n*4+2]*Bbank[co*4+2] + pi[n*4+3]*Bbank[co*4+3];
  }

  f32x4 acc[2][4][4];
#pragma unroll
  for (int o = 0; o < 2; ++o)
#pragma unroll
    for (int a = 0; a < 4; ++a)
#pragma unroll
      for (int b = 0; b < 4; ++b)
#pragma unroll
        for (int k = 0; k < 4; ++k) acc[o][a][b][k] = 0.f;

  const bf16* wnb = wn + (size_t)n * 1152 * 512;

  for (int c = 0; c < 8; ++c) {
    __syncthreads();             // previous chunk's compute done before overwrite
    // stage weights: wave wv stages cb=wv: 9 DMAs, width 16
    {
      const bf16* seg = wnb + (size_t)c*144*512 + (size_t)(cot*4 + wv)*512 + lane*8;
#pragma unroll
      for (int kk = 0; kk < 9; ++kk)
        async16(&wa[kk*2048 + wv*512], seg + (size_t)kk*16*512);
    }
    // stage x: wave wv stages ci-group wv, 10 rows (halo rows skipped -> stay zero)
    {
      const bf16* xg = xb + ((size_t)(n*32 + c*4 + wv))*4096*8 + lane*8;
#pragma unroll
      for (int r = 0; r < XROWS; ++r) {
        int hp = h0 - 1 + r;
        if (hp >= 0 && hp < HH)
          async16(&xs[((wv*XROWS + r)*XW + 1)*8], xg + (size_t)hp*64*8);
      }
    }
    __syncthreads();
    // compute: 3 kx { load 16 B-frags; 3 ky x 4 cb x (2 rows x 4 f MFMA) }
#pragma unroll
    for (int kx = 0; kx < 3; ++kx) {
      bf16x8 bfr[4][4];
#pragma unroll
      for (int rr = 0; rr < 4; ++rr)
#pragma unroll
        for (int f = 0; f < 4; ++f)
          bfr[rr][f] = *(const bf16x8*)(&xs[((u*XROWS + wv*2 + rr)*XW + f*16 + l + kx)*8]);
#pragma unroll
      for (int ky = 0; ky < 3; ++ky) {
        const int kk = ky*3 + kx;
#pragma unroll
        for (int cb = 0; cb < 4; ++cb) {
          bf16x8 afr = *(const bf16x8*)(&wa[kk*2048 + cb*512 + lane*8]);
#pragma unroll
          for (int o = 0; o < 2; ++o)
#pragma unroll
            for (int f = 0; f < 4; ++f)
              acc[o][cb][f] = __builtin_amdgcn_mfma_f32_16x16x32_bf16(afr, bfr[o+ky][f], acc[o][cb][f], 0, 0, 0);
        }
      }
    }
  }
  // epilogue: D row=(lane>>4)*4+reg -> co, col=lane&15 -> w
#pragma unroll
  for (int o = 0; o < 2; ++o) {
    const int h = h0 + wv*2 + o;
#pragma unroll
    for (int cb = 0; cb < 4; ++cb) {
#pragma unroll
      for (int f = 0; f < 4; ++f) {
        const int wcol = f*16 + l;
#pragma unroll
        for (int r4 = 0; r4 < 4; ++r4) {
          const int col = cb*16 + u*4 + r4;
          y[(((size_t)n*CO + cot*64 + col)*HH + h)*WW + wcol] = acc[o][cb][f][r4] + bns[col];
        }
      }
    }
  }
}

extern "C" void kernel_launch(void* const* d_in, const int* in_sizes, int n_in,
                              void* d_out, int out_size, void* d_ws, size_t ws_size,
                              hipStream_t stream) {
  const float* x     = (const float*)d_in[0];
  const float* Wbank = (const float*)d_in[1];
  const float* Bbank = (const float*)d_in[2];
  const float* w1    = (const float*)d_in[3];
  const float* b1    = (const float*)d_in[4];
  const float* w2    = (const float*)d_in[5];
  const float* b2    = (const float*)d_in[6];
  float* y = (float*)d_out;

  bf16*  wn     = (bf16*)d_ws;                                  // 37.75 MB
  bf16*  xb     = (bf16*)((char*)d_ws + WN_BYTES);              // 64 MB
  float* pooled = (float*)((char*)d_ws + WN_BYTES + XB_BYTES);  // 32 KB
  float* pi     = pooled + NB*CI;                               // 512 B

  dim3 cg(32, NB);
  cvt_pool_kernel<<<cg, 256, 0, stream>>>(x, xb, pooled);
  attn_kernel<<<NB, HID, 0, stream>>>(pooled, w1, b1, w2, b2, pi);
  agg_kernel<<<288, 256, 0, stream>>>(Wbank, pi, wn);
  dim3 grid(8, 4, NB);
  conv_kernel<<<grid, 256, 0, stream>>>(xb, wn, pi, Bbank, y);
}